// Round 13
// baseline (402.376 us; speedup 1.0000x reference)
//
#include <hip/hip_runtime.h>

// SRLoss: loss = mean((inp - avgpool10x10(output))^2) + BCE(output, target)
// output/target: [32,1,1280,1280] f32; inp: [32,1,128,128] f32; out: scalar f32.
//
// R16 post-mortem: staged+NT = 388.6us. Beats pre-nt R12 (407) -> NT bit
// works on global_load_lds; loses to register-nt R14 (376.5) -> R12's
// per-chunk __syncthreads vmcnt(0) FULL DRAIN serializes the forced
// pipeline. Forced-in-flight and no-drain have never coexisted.
// R17: both at once (guide T3/T4, counted vmcnt, never 0 mid-loop) — and
// exploit that staging here is WAVE-LOCAL (each wave reads only the LDS
// bytes it staged) so mid-kernel barriers vanish entirely. NT=640, whole
// band in LDS (100KB, 1 block/CU, 10 waves), per wave 10 stages (o,t per
// step, order pinned by sched_barrier(0)), compute step k after
// s_waitcnt vmcnt(8-2k): steps k+1..4 stay in flight under compute.
// Pre-commit: absmax!=0 -> counted-vmcnt broke, revert R15. 70-90us partial
// (bench ~340-360) = win. ~375 = nt-read ceiling -> ROOFLINE+revert next.
// >390 = 1-block/CU tail hurts -> revert R15.

#define BATCH 32
#define HH 1280
#define WW 1280
#define PH 128
#define PW 128
#define SC 10
#define NT 640                      // threads per block (10 waves)
#define KD 5                        // steps: 2 rows (1 o + 1 t float4) per step
#define NB (BATCH * PH)             // 4096 bands = 4096 blocks
#define NT2 512                     // reduce-kernel threads

static constexpr float EPSV = 1e-20f;
static constexpr float LN2  = 0.6931471805599453f;
static constexpr float INV_NBCE = 1.0f / (float)(BATCH * HH * WW);   // bce mean
static constexpr float INV_NM   = 1.0f / (float)(BATCH * PH * PW);   // mse mean

// Async global->LDS, 16B per lane, NT cache policy (aux=2).
#define STAGE16NT(gp, lp)                                                 \
    __builtin_amdgcn_global_load_lds(                                     \
        (const __attribute__((address_space(1))) void*)(const void*)(gp), \
        (__attribute__((address_space(3))) void*)(void*)(lp), 16, 0, 2)

__global__ __launch_bounds__(NT, 2) void srloss_partial(
    const float* __restrict__ output,
    const float* __restrict__ target,
    const float* __restrict__ inp,
    float* __restrict__ partials)
{
    __shared__ float so[SC * WW];   // whole band, output: 51,200 B
    __shared__ float st[SC * WW];   // whole band, target: 51,200 B
    __shared__ float psum[PW];      // pooled column sums
    __shared__ float red[NT / 64];  // cross-wave reduction scratch

    const int t = threadIdx.x;
    const int band = blockIdx.x;    // 0 .. BATCH*PH-1
    const int b = band >> 7;        // band / 128
    const int pr = band & 127;      // band % 128

    if (t < PW) psum[t] = 0.0f;
    __syncthreads();                // vmcnt==0 here, drain is free

    const size_t base = ((size_t)b * HH + (size_t)pr * SC) * WW;
    // step k: float4 index t + 640k -> float offset 4t + 2560k
    const float* op = output + base + 4 * t;
    const float* tp = target + base + 4 * t;

    // LDS dest: wave-uniform base + lane*16. Wave w, step k covers floats
    // [256w + 2560k, +256) == exactly the float4s this wave's lanes read.
    const int wbase = (t >> 6) << 8;   // wave_id * 256 floats

    // Issue ALL 10 stages per wave, order pinned. FIFO: step k's pair are
    // ops 2k, 2k+1 -> both complete when <= 8-2k remain outstanding.
    #pragma unroll
    for (int k = 0; k < KD; ++k) {
        STAGE16NT(op + 2560 * k, &so[wbase + 2560 * k]);
        __builtin_amdgcn_sched_barrier(0);
        STAGE16NT(tp + 2560 * k, &st[wbase + 2560 * k]);
        __builtin_amdgcn_sched_barrier(0);
    }

    // col mapping: float4 index t+640k -> col4 = t%320 (k-invariant)
    const int c320 = (t >= 320) ? (t - 320) : t;   // t % 320
    const int c0 = 4 * c320;
    const int p0 = c0 / SC;
    const bool straddle = (c0 % SC) == 8;          // elems 2,3 -> p0+1

    float acc2 = 0.0f;              // sum log2(oc)
    float accd = 0.0f;              // sum t*(log2(om)-log2(oc))
    float s0 = 0.0f, s1 = 0.0f;     // pooled sums: halves of the float4

    #pragma unroll
    for (int k = 0; k < KD; ++k) {
        // counted wait: steps k+1..4 (2*(4-k) loads) stay in flight
        if      (k == 0) asm volatile("s_waitcnt vmcnt(8)" ::: "memory");
        else if (k == 1) asm volatile("s_waitcnt vmcnt(6)" ::: "memory");
        else if (k == 2) asm volatile("s_waitcnt vmcnt(4)" ::: "memory");
        else if (k == 3) asm volatile("s_waitcnt vmcnt(2)" ::: "memory");
        else             asm volatile("s_waitcnt vmcnt(0)" ::: "memory");
        __builtin_amdgcn_sched_barrier(0);   // rule #18: pin reads below wait

        const float4 o4 = *(const float4*)&so[4 * t + 2560 * k];
        const float4 t4 = *(const float4*)&st[4 * t + 2560 * k];
        const float o[4]  = {o4.x, o4.y, o4.z, o4.w};
        const float tg[4] = {t4.x, t4.y, t4.z, t4.w};
        #pragma unroll
        for (int j = 0; j < 4; ++j) {
            const float om = fmaxf(o[j], EPSV);
            const float oc = fmaxf(1.0f - o[j], EPSV);
            const float l1 = __log2f(om);
            const float l2 = __log2f(oc);
            acc2 += l2;
            accd += tg[j] * (l1 - l2);
        }
        s0 += o[0] + o[1];
        s1 += o[2] + o[3];
    }
    const float bce_acc = LN2 * (acc2 + accd);

    if (straddle) {
        atomicAdd(&psum[p0],     s0);
        atomicAdd(&psum[p0 + 1], s1);
    } else {
        atomicAdd(&psum[p0], s0 + s1);
    }
    __syncthreads();                // vmcnt already 0; lgkm drain for atomics

    // MSE terms: one pooled element per thread for t < 128
    float mse_acc = 0.0f;
    if (t < PW) {
        const float pooled = psum[t] * (1.0f / (float)(SC * SC));
        const float iv = inp[(size_t)band * PW + t];
        const float d = iv - pooled;
        mse_acc = d * d;
    }

    // per-block contribution, pre-normalized
    float contrib = (-INV_NBCE) * bce_acc + INV_NM * mse_acc;

    #pragma unroll
    for (int off = 32; off > 0; off >>= 1)
        contrib += __shfl_down(contrib, off, 64);
    if ((t & 63) == 0) red[t >> 6] = contrib;
    __syncthreads();

    // plain store to a distinct slot: no RMW chain, no fence
    if (t == 0) {
        float s = 0.0f;
        #pragma unroll
        for (int w = 0; w < NT / 64; ++w) s += red[w];
        partials[band] = s;
    }
}

__global__ __launch_bounds__(NT2) void srloss_reduce(
    const float* __restrict__ partials,
    float* __restrict__ out)
{
    __shared__ float red[NT2 / 64];
    const int t = threadIdx.x;

    // 4096 floats = 1024 float4; 512 threads x 2 float4 each
    const float4 v0 = ((const float4*)partials)[t];
    const float4 v1 = ((const float4*)partials)[t + NT2];
    float s = (v0.x + v0.y) + (v0.z + v0.w) + (v1.x + v1.y) + (v1.z + v1.w);

    #pragma unroll
    for (int off = 32; off > 0; off >>= 1)
        s += __shfl_down(s, off, 64);
    if ((t & 63) == 0) red[t >> 6] = s;
    __syncthreads();
    if (t == 0) {
        float tot = 0.0f;
        #pragma unroll
        for (int w = 0; w < NT2 / 64; ++w) tot += red[w];
        out[0] = tot;
    }
}

extern "C" void kernel_launch(void* const* d_in, const int* in_sizes, int n_in,
                              void* d_out, int out_size, void* d_ws, size_t ws_size,
                              hipStream_t stream) {
    const float* output = (const float*)d_in[0];
    const float* target = (const float*)d_in[1];
    const float* inp    = (const float*)d_in[2];
    float* out = (float*)d_out;
    float* partials = (float*)d_ws;              // 4096 floats = 16 KB

    srloss_partial<<<NB, NT, 0, stream>>>(output, target, inp, partials);
    srloss_reduce<<<1, NT2, 0, stream>>>(partials, out);
}

// Round 14
// 374.095 us; speedup vs baseline: 1.0756x; 1.0756x over previous
//
#include <hip/hip_runtime.h>

// SRLoss: loss = mean((inp - avgpool10x10(output))^2) + BCE(output, target)
// output/target: [32,1,1280,1280] f32; inp: [32,1,128,128] f32; out: scalar f32.
//
// R17 post-mortem: wave-local counted-vmcnt pipeline = 402us (>390 branch:
// the 100KB-LDS/1-block-CU residency cost swamped the pipeline gain).
// Register-nt (R14/R15, ~105us partial, 4.0 TB/s read) remains best.
// R18 (last probe before roofline): true register full-preload under nt.
// R9's asm-volatile loads were defeated legally — compute hoisted BETWEEN
// volatile asms, registers reused (VGPR stayed 44). Fix = rule #17 keep-alive
// as a convergence point: 20 nt loads -> ONE dummy asm reading all 20 float4s
// (data-dep forces all loads complete + 80 VGPRs simultaneously live; the
// compiler emits a single vmcnt(0) there) -> sched_barrier(0) -> compute.
// 20KB/wave in flight, no LDS, no barriers, no residency cost.
// Pre-commit: VGPR ~100-120 else idiom failed (revert R15, roofline).
// Partial -> 70-85us = win. VGPR jumps + dur ~375 = per-CU MSHR cap ->
// ROOFLINE next round, revert R15.

#define BATCH 32
#define HH 1280
#define WW 1280
#define PH 128
#define PW 128
#define SC 10
#define NT 320                      // threads per block (5 waves)
#define KD 10                       // float4-pair iterations per thread
#define NB (BATCH * PH)             // 4096 bands = 4096 blocks
#define NT2 512                     // reduce-kernel threads

typedef float f32x4 __attribute__((ext_vector_type(4)));

static constexpr float EPSV = 1e-20f;
static constexpr float LN2  = 0.6931471805599453f;
static constexpr float INV_NBCE = 1.0f / (float)(BATCH * HH * WW);   // bce mean
static constexpr float INV_NM   = 1.0f / (float)(BATCH * PH * PW);   // mse mean

__device__ __forceinline__ f32x4 ntload4(const f32x4* p) {
    return __builtin_nontemporal_load(p);
}

__global__ __launch_bounds__(NT, 4) void srloss_partial(
    const float* __restrict__ output,
    const float* __restrict__ target,
    const float* __restrict__ inp,
    float* __restrict__ partials)
{
    __shared__ float psum[PW];      // pooled column sums for this band
    __shared__ float red[NT / 64];  // cross-wave reduction scratch

    const int t = threadIdx.x;
    const int band = blockIdx.x;    // 0 .. BATCH*PH-1
    const int b = band >> 7;        // band / 128
    const int pr = band & 127;      // band % 128

    if (t < PW) psum[t] = 0.0f;
    __syncthreads();                // before any loads issue

    const size_t base = ((size_t)b * HH + (size_t)pr * SC) * WW;
    const f32x4* __restrict__ o4p = (const f32x4*)(output + base) + t;
    const f32x4* __restrict__ t4p = (const f32x4*)(target + base) + t;

    // full preload, non-temporal: 20 x 16B per lane = 20 KB in flight/wave
    f32x4 ob[KD], tb[KD];
    #pragma unroll
    for (int k = 0; k < KD; ++k) {
        ob[k] = ntload4(o4p + NT * k);
        tb[k] = ntload4(t4p + NT * k);
    }
    // keep-alive convergence point: reads ALL 20 results -> every load must
    // complete here (one vmcnt(0)) and all 80 dest VGPRs are live at once.
    asm volatile("" ::
        "v"(ob[0]), "v"(ob[1]), "v"(ob[2]), "v"(ob[3]), "v"(ob[4]),
        "v"(ob[5]), "v"(ob[6]), "v"(ob[7]), "v"(ob[8]), "v"(ob[9]),
        "v"(tb[0]), "v"(tb[1]), "v"(tb[2]), "v"(tb[3]), "v"(tb[4]),
        "v"(tb[5]), "v"(tb[6]), "v"(tb[7]), "v"(tb[8]), "v"(tb[9]));
    __builtin_amdgcn_sched_barrier(0);   // nothing hoists above this point

    float acc2 = 0.0f;              // sum log2(oc)
    float accd = 0.0f;              // sum t*(log2(om)-log2(oc))
    float s0 = 0.0f, s1 = 0.0f;     // pooled sums: halves of the float4
    #pragma unroll
    for (int k = 0; k < KD; ++k) {
        const f32x4 o4 = ob[k];
        const f32x4 t4 = tb[k];
        #pragma unroll
        for (int j = 0; j < 4; ++j) {
            const float oj = o4[j];
            const float om = fmaxf(oj, EPSV);
            const float oc = fmaxf(1.0f - oj, EPSV);
            const float l1 = __log2f(om);
            const float l2 = __log2f(oc);
            acc2 += l2;
            accd += t4[j] * (l1 - l2);
        }
        s0 += o4[0] + o4[1];
        s1 += o4[2] + o4[3];
    }
    const float bce_acc = LN2 * (acc2 + accd);

    // c = t + 320k -> row = k, col0 = 4t for all k (k-invariant mapping)
    const int col0 = 4 * t;
    const int p0 = col0 / SC;
    if ((col0 % SC) == 8) {         // straddle: elems 2,3 belong to p0+1
        atomicAdd(&psum[p0],     s0);
        atomicAdd(&psum[p0 + 1], s1);
    } else {
        atomicAdd(&psum[p0], s0 + s1);
    }
    __syncthreads();

    // MSE terms: one pooled element per thread for t < 128
    float mse_acc = 0.0f;
    if (t < PW) {
        const float pooled = psum[t] * (1.0f / (float)(SC * SC));
        const float iv = inp[(size_t)band * PW + t];
        const float d = iv - pooled;
        mse_acc = d * d;
    }

    // per-block contribution, pre-normalized
    float contrib = (-INV_NBCE) * bce_acc + INV_NM * mse_acc;

    #pragma unroll
    for (int off = 32; off > 0; off >>= 1)
        contrib += __shfl_down(contrib, off, 64);
    if ((t & 63) == 0) red[t >> 6] = contrib;
    __syncthreads();

    // plain store to a distinct slot: no RMW chain, no fence
    if (t == 0) {
        float s = 0.0f;
        #pragma unroll
        for (int w = 0; w < NT / 64; ++w) s += red[w];
        partials[band] = s;
    }
}

__global__ __launch_bounds__(NT2) void srloss_reduce(
    const float* __restrict__ partials,
    float* __restrict__ out)
{
    __shared__ float red[NT2 / 64];
    const int t = threadIdx.x;

    // 4096 floats = 1024 float4; 512 threads x 2 float4 each
    const f32x4 v0 = ((const f32x4*)partials)[t];
    const f32x4 v1 = ((const f32x4*)partials)[t + NT2];
    float s = (v0[0] + v0[1]) + (v0[2] + v0[3]) + (v1[0] + v1[1]) + (v1[2] + v1[3]);

    #pragma unroll
    for (int off = 32; off > 0; off >>= 1)
        s += __shfl_down(s, off, 64);
    if ((t & 63) == 0) red[t >> 6] = s;
    __syncthreads();
    if (t == 0) {
        float tot = 0.0f;
        #pragma unroll
        for (int w = 0; w < NT2 / 64; ++w) tot += red[w];
        out[0] = tot;
    }
}

extern "C" void kernel_launch(void* const* d_in, const int* in_sizes, int n_in,
                              void* d_out, int out_size, void* d_ws, size_t ws_size,
                              hipStream_t stream) {
    const float* output = (const float*)d_in[0];
    const float* target = (const float*)d_in[1];
    const float* inp    = (const float*)d_in[2];
    float* out = (float*)d_out;
    float* partials = (float*)d_ws;              // 4096 floats = 16 KB

    srloss_partial<<<NB, NT, 0, stream>>>(output, target, inp, partials);
    srloss_reduce<<<1, NT2, 0, stream>>>(partials, out);
}